// Round 3
// baseline (86.411 us; speedup 1.0000x reference)
//
#include <hip/hip_runtime.h>
#include <math.h>

// S4D kernel generation: K[h,l] = 2*Re( sum_n Ck[h,n] * exp(dtA[h,n]*l) )
// H=1024, N2=32, L=4096. Output (H,L) fp32.
//
// Two kernels:
//  1) prep: one thread per (h,n) does all fp64 work (discretization, w^256
//     by squaring) and writes a 32-B coeff record + fp64 phase slope to d_ws.
//  2) main: grid (H, 2), 256 threads; thread t of half-block q owns
//     l = 2048q + t + 256j, j=0..7. Per mode: anchor from fp64-reduced phase
//     (HW v_sin/v_cos take revolutions), then the stable real recurrence
//     s_j = p*s_{j-1} - q*s_{j-2} (p=2Re(W), q=|W|^2, W=w^256), 3 ops/step.
//     Coeff reads are wave-uniform -> scalar loads; no LDS, no barrier.

#define N2 32
#define L_LEN 4096
#define NTHREADS 256
#define JTILE 8          // 8 j-steps per thread; L covered by 2 half-blocks
#define HALF_L 2048

struct Coef {            // 32 B, s_load_dwordx8-friendly
  float x;               // Re(dtA)
  float ckr, cki;        // 2 * Cc * (w-1)/A
  float Wr, Wi;          // W = w^256
  float p, q;            // 2*Re(W), |W|^2
  float pad;
};

__global__ __launch_bounds__(256) void s4d_prep_kernel(
    const float* __restrict__ log_dt,      // (H,)
    const float* __restrict__ Cri,         // (H, N2, 2)
    const float* __restrict__ log_A_real,  // (H, N2)
    const float* __restrict__ A_imag,      // (H, N2)
    double* __restrict__ yrev,             // (H*N2,) phase revolutions per l
    Coef* __restrict__ cf)                 // (H*N2,)
{
  const int idx = blockIdx.x * 256 + threadIdx.x;   // h*N2 + n
  const int h = idx >> 5;

  const double dt = exp((double)log_dt[h]);
  const double Ar = -exp((double)log_A_real[idx]);
  const double Ai = (double)A_imag[idx];
  const double xr = dt * Ar;
  const double xi = dt * Ai;
  const double ex = exp(xr);
  const double wr = ex * cos(xi);     // w = exp(dtA)
  const double wi = ex * sin(xi);
  // f = (w-1)/A via (w-1)*conj(A)/|A|^2
  const double nr = wr - 1.0, ni = wi;
  const double inv = 1.0 / (Ar * Ar + Ai * Ai);
  const double fr = (nr * Ar + ni * Ai) * inv;
  const double fi = (ni * Ar - nr * Ai) * inv;
  const double c0 = (double)Cri[idx * 2 + 0];
  const double c1 = (double)Cri[idx * 2 + 1];
  // W = w^256 by 8 complex squarings
  double ar = wr, ai = wi;
#pragma unroll
  for (int k = 0; k < 8; ++k) {
    const double tr = ar * ar - ai * ai;
    const double ti = 2.0 * ar * ai;
    ar = tr; ai = ti;
  }
  Coef c;
  c.x   = (float)xr;
  c.ckr = (float)(2.0 * (c0 * fr - c1 * fi));
  c.cki = (float)(2.0 * (c0 * fi + c1 * fr));
  c.Wr  = (float)ar;
  c.Wi  = (float)ai;
  c.p   = (float)(2.0 * ar);
  c.q   = (float)(ar * ar + ai * ai);
  c.pad = 0.0f;
  cf[idx] = c;
  yrev[idx] = xi * 0.15915494309189535;  // xi / (2*pi)
}

__global__ __launch_bounds__(NTHREADS) void s4d_main_kernel(
    const double* __restrict__ yrev,
    const Coef* __restrict__ cf,
    float* __restrict__ out)               // (H, L)
{
  const int h = blockIdx.x;
  const int l0 = blockIdx.y * HALF_L + threadIdx.x;
  const float  lf = (float)l0;
  const double ld = (double)l0;

  float acc[JTILE];
#pragma unroll
  for (int j = 0; j < JTILE; ++j) acc[j] = 0.0f;

  const int base = h * N2;
#pragma unroll 4
  for (int n = 0; n < N2; ++n) {
    const Coef c = cf[base + n];              // wave-uniform -> scalar loads
    double ph = yrev[base + n] * ld;
    ph -= floor(ph);                          // exact fract in [0,1)
    const float frac = (float)ph;
    const float sn = __builtin_amdgcn_sinf(frac);  // sin(2*pi*frac)
    const float cs = __builtin_amdgcn_cosf(frac);
    const float e  = __expf(c.x * lf);
    const float vr = e * cs;
    const float vi = e * sn;
    const float ur = fmaf(c.ckr, vr, -(c.cki * vi));
    const float ui = fmaf(c.ckr, vi,  c.cki * vr);
    float s0 = ur;
    float s1 = fmaf(ur, c.Wr, -(ui * c.Wi));
    acc[0] += s0;
    acc[1] += s1;
#pragma unroll
    for (int j = 2; j < JTILE; ++j) {
      const float s2 = fmaf(c.p, s1, -(c.q * s0));
      acc[j] += s2;
      s0 = s1; s1 = s2;
    }
  }

  float* o = out + (size_t)h * L_LEN + l0;
#pragma unroll
  for (int j = 0; j < JTILE; ++j) o[j * NTHREADS] = acc[j];
}

extern "C" void kernel_launch(void* const* d_in, const int* in_sizes, int n_in,
                              void* d_out, int out_size, void* d_ws, size_t ws_size,
                              hipStream_t stream) {
  const float* log_dt     = (const float*)d_in[0];
  const float* Cri        = (const float*)d_in[1];
  const float* log_A_real = (const float*)d_in[2];
  const float* A_imag     = (const float*)d_in[3];
  float* out = (float*)d_out;
  const int H = in_sizes[0];

  double* yrev = (double*)d_ws;                                  // 256 KB
  Coef*   cf   = (Coef*)((char*)d_ws + (size_t)H * N2 * sizeof(double));

  s4d_prep_kernel<<<dim3(H * N2 / 256), dim3(256), 0, stream>>>(
      log_dt, Cri, log_A_real, A_imag, yrev, cf);
  s4d_main_kernel<<<dim3(H, 2), dim3(NTHREADS), 0, stream>>>(yrev, cf, out);
}